// Round 3
// baseline (241.471 us; speedup 1.0000x reference)
//
#include <hip/hip_runtime.h>
#include <hip/hip_bf16.h>
#include <math.h>

#define NB 16
#define NS 1024
#define NM 256
#define NH 8
#define NDK 32
#define NL 2

typedef __attribute__((ext_vector_type(4))) float f32x4;
typedef __attribute__((ext_vector_type(8))) short bf16x8;
typedef __attribute__((ext_vector_type(4))) short bf16x4u;

#if __has_builtin(__builtin_amdgcn_exp2f)
#define EXP2F(x) __builtin_amdgcn_exp2f(x)
#else
#define EXP2F(x) exp2f(x)
#endif

__device__ __forceinline__ unsigned short f2bf(float f) {
  unsigned int u = __builtin_bit_cast(unsigned int, f);
  unsigned int r = u + 0x7fffu + ((u >> 16) & 1u);
  return (unsigned short)(r >> 16);
}
__device__ __forceinline__ float bf2f(unsigned short h) {
  unsigned int u = ((unsigned int)h) << 16;
  return __builtin_bit_cast(float, u);
}

// ---------------------------------------------------------------------------
// Pack (smask || adj==0) and (smask) into bitmasks, 1 bit per (b,i,j).
__global__ __launch_bounds__(256) void maskpack_kernel(
    const int* __restrict__ adj, const int* __restrict__ sm,
    unsigned int* __restrict__ pkc, unsigned int* __restrict__ pks)
{
  int t = blockIdx.x * 256 + threadIdx.x;
  long base = (long)t * 32;
  const int4* a4 = (const int4*)(adj + base);
  const int4* m4 = (const int4*)(sm + base);
  union { int4 v[8]; int b[32]; } au, mu;
#pragma unroll
  for (int q = 0; q < 8; ++q) { au.v[q] = a4[q]; mu.v[q] = m4[q]; }
  unsigned int wc = 0, wsb = 0;
#pragma unroll
  for (int e = 0; e < 32; ++e) {
    unsigned int msk = mu.b[e] ? 1u : 0u;
    unsigned int cmb = (mu.b[e] || au.b[e] == 0) ? 1u : 0u;
    wsb |= msk << e;
    wc  |= cmb << e;
  }
  pkc[t] = wc; pks[t] = wsb;
}

// ---------------------------------------------------------------------------
// Projection GEMM -> Pt[b][h][d][s] (bf16), 64x64 tile, 4 waves.
__global__ __launch_bounds__(256) void proj_kernel(
    const float* __restrict__ x,        // (B*S, M)
    const float* __restrict__ pw,       // (H, M, DK) this layer
    const float* __restrict__ pb,       // (H*DK)
    unsigned short* __restrict__ Pt)    // (B,H,DK,S)
{
  __shared__ unsigned short As[64][40];
  __shared__ unsigned short Bs[64][40];

  int ct = blockIdx.x;
  int rt = blockIdx.y;
  int t = threadIdx.x;
  int w = t >> 6, lane = t & 63;
  int il = lane & 15, g4 = lane >> 4;
  int wi = w >> 1, wc = w & 1;

  f32x4 acc[2][2] = {};

  int arow = t >> 2, akoff = (t & 3) * 8;
  int bcol = t & 63, bk0 = (t >> 6) * 8;
  int hd = ct * 64 + bcol;
  int h = hd >> 5, d = hd & 31;

  for (int k0 = 0; k0 < NM; k0 += 32) {
    const float* xp = x + (size_t)(rt * 64 + arow) * NM + k0 + akoff;
    f32x4 v0 = *(const f32x4*)xp;
    f32x4 v1 = *(const f32x4*)(xp + 4);
    bf16x8 av;
    av[0] = f2bf(v0[0]); av[1] = f2bf(v0[1]); av[2] = f2bf(v0[2]); av[3] = f2bf(v0[3]);
    av[4] = f2bf(v1[0]); av[5] = f2bf(v1[1]); av[6] = f2bf(v1[2]); av[7] = f2bf(v1[3]);
    *(bf16x8*)&As[arow][akoff] = av;
    const float* wp = pw + (size_t)h * NM * NDK + (size_t)(k0 + bk0) * NDK + d;
    bf16x8 bv;
#pragma unroll
    for (int q = 0; q < 8; ++q) bv[q] = f2bf(wp[q * NDK]);
    *(bf16x8*)&Bs[bcol][bk0] = bv;
    __syncthreads();

    bf16x8 af0 = *(bf16x8*)&As[wi * 32 + il][g4 * 8];
    bf16x8 af1 = *(bf16x8*)&As[wi * 32 + 16 + il][g4 * 8];
    bf16x8 bf0 = *(bf16x8*)&Bs[wc * 32 + il][g4 * 8];
    bf16x8 bf1 = *(bf16x8*)&Bs[wc * 32 + 16 + il][g4 * 8];
    acc[0][0] = __builtin_amdgcn_mfma_f32_16x16x32_bf16(af0, bf0, acc[0][0], 0, 0, 0);
    acc[0][1] = __builtin_amdgcn_mfma_f32_16x16x32_bf16(af0, bf1, acc[0][1], 0, 0, 0);
    acc[1][0] = __builtin_amdgcn_mfma_f32_16x16x32_bf16(af1, bf0, acc[1][0], 0, 0, 0);
    acc[1][1] = __builtin_amdgcn_mfma_f32_16x16x32_bf16(af1, bf1, acc[1][1], 0, 0, 0);
    __syncthreads();
  }

#pragma unroll
  for (int ih = 0; ih < 2; ++ih) {
#pragma unroll
    for (int dh = 0; dh < 2; ++dh) {
      int colhd = ct * 64 + wc * 32 + dh * 16 + il;
      int hh = colhd >> 5, dd = colhd & 31;
      float bias = pb[colhd];
      int r0 = rt * 64 + wi * 32 + ih * 16 + g4 * 4;
      int bb = r0 >> 10, ss = r0 & 1023;
      f32x4 c = acc[ih][dh];
      unsigned short ov[4];
#pragma unroll
      for (int e = 0; e < 4; ++e) ov[e] = f2bf(c[e] + bias);
      size_t idx = ((size_t)(bb * NH + hh) * NDK + dd) * NS + ss;
      *(bf16x4u*)(Pt + idx) = *(bf16x4u*)ov;
    }
  }
}

// ---------------------------------------------------------------------------
// s1/s2 PRE-SCALED by log2(e) so attn uses native exp2.
__global__ __launch_bounds__(256) void s_kernel(
    const unsigned short* __restrict__ Pt,
    const float* __restrict__ aw,   // 64 floats this layer
    const float* __restrict__ abp,  // attn_b + l
    float* __restrict__ s1o, float* __restrict__ s2o)
{
  const float LOG2E = 1.4426950408889634f;
  int t = blockIdx.x * 256 + threadIdx.x;   // (b*H+h)*S + s
  int bh = t >> 10, s = t & 1023;
  const unsigned short* p = Pt + (size_t)bh * NDK * NS + s;
  float s1 = 0.f, s2 = 0.f;
#pragma unroll
  for (int dd = 0; dd < NDK; ++dd) {
    float pv = bf2f(p[dd * NS]);
    s1 += pv * aw[dd];
    s2 += pv * aw[32 + dd];
  }
  s1o[t] = s1 * LOG2E;
  s2o[t] = (s2 + abp[0]) * LOG2E;
}

// ---------------------------------------------------------------------------
// Fused attention + residual + LayerNorm.
// Block = one (b, 16-row i-tile). 4 waves; wave w owns heads {2w, 2w+1}.
// Grid = B * (S/16) = 1024 blocks (4 blocks/CU -> 16 waves/CU).
__global__ __launch_bounds__(256) void attn_kernel(
    const float* __restrict__ xin,            // residual input (B,S,M) f32
    const unsigned short* __restrict__ Pt,    // (B,H,DK,S) bf16
    const float* __restrict__ s1a,            // (B,H,S), pre-scaled log2e
    const float* __restrict__ s2a,            // (B,H,S), pre-scaled, incl +ab
    const unsigned int* __restrict__ pkc,     // combined mask bits
    const unsigned int* __restrict__ pks,     // smask-only bits
    const int* __restrict__ typep,
    int layer,
    const float* __restrict__ lng,
    const float* __restrict__ lnb,
    float* __restrict__ xout)
{
  __shared__ float lds_c[16][260];   // concat tile (260 % 32 == 4 -> 2-way max)
  __shared__ float lds_den[8][16];   // softmax denominators per head/row

  int blk = blockIdx.x;
  int b = blk >> 6, it = blk & 63, i0 = it * 16;
  int t = threadIdx.x, w = t >> 6, lane = t & 63;
  int il = lane & 15, g4 = lane >> 4;
  int h0 = w * 2;
  const unsigned char* pkb =
      (const unsigned char*)((typep[0] == 1 && layer > 0) ? pks : pkc);
  size_t rowbase = ((size_t)(b * NS + i0 + il) * NS) >> 3;  // byte index

  float s1v[2];
#pragma unroll
  for (int hh = 0; hh < 2; ++hh)
    s1v[hh] = s1a[(size_t)(b * NH + h0 + hh) * NS + i0 + il];

  f32x4 acc[2][2] = {};
  float dsum[2] = {};
  const unsigned short* ptb = Pt + (size_t)(b * NH + h0) * NDK * NS;

  for (int j0 = 0; j0 < NS; j0 += 32) {
    int jb = j0 + g4 * 8;
    unsigned int mb = pkb[rowbase + (jb >> 3)];
#pragma unroll
    for (int hh = 0; hh < 2; ++hh) {
      const float* s2p = s2a + (size_t)(b * NH + h0 + hh) * NS + jb;
      f32x4 s2lo = *(const f32x4*)s2p;
      f32x4 s2hi = *(const f32x4*)(s2p + 4);
      float s2v[8] = {s2lo[0], s2lo[1], s2lo[2], s2lo[3],
                      s2hi[0], s2hi[1], s2hi[2], s2hi[3]};
      bf16x8 bf0 = *(const bf16x8*)(ptb + ((size_t)hh * NDK + il) * NS + jb);
      bf16x8 bf1 = *(const bf16x8*)(ptb + ((size_t)hh * NDK + 16 + il) * NS + jb);
      float wv[8];
      float ds = 0.f;
#pragma unroll
      for (int e = 0; e < 8; ++e) {
        float sc = s1v[hh] + s2v[e];
        sc = fmaxf(sc, 0.2f * sc);             // LeakyReLU(0.2), scale>0 commutes
        float ex = EXP2F(sc);                  // scores pre-scaled by log2e
        ex = (mb & (1u << e)) ? 0.f : ex;
        wv[e] = ex;
        ds += ex;
      }
      dsum[hh] += ds;
      bf16x8 af;
#pragma unroll
      for (int e = 0; e < 8; ++e)
        af[e] = (short)__bfloat16_as_ushort(__float2bfloat16(wv[e]));
      acc[hh][0] = __builtin_amdgcn_mfma_f32_16x16x32_bf16(af, bf0, acc[hh][0], 0, 0, 0);
      acc[hh][1] = __builtin_amdgcn_mfma_f32_16x16x32_bf16(af, bf1, acc[hh][1], 0, 0, 0);
    }
  }

  // reduce denominators across the 4 k-groups (lanes differing in bits 4,5)
#pragma unroll
  for (int hh = 0; hh < 2; ++hh) {
    float v = dsum[hh];
    v += __shfl_xor(v, 16, 64);
    v += __shfl_xor(v, 32, 64);
    dsum[hh] = v;
  }
  if (g4 == 0) {
#pragma unroll
    for (int hh = 0; hh < 2; ++hh) lds_den[h0 + hh][il] = dsum[hh];
  }
  __syncthreads();

  // normalize + scatter concat tile to LDS (C layout: col=il, row=g4*4+e)
#pragma unroll
  for (int hh = 0; hh < 2; ++hh) {
    f32x4 dn = *(f32x4*)&lds_den[h0 + hh][g4 * 4];
#pragma unroll
    for (int dh = 0; dh < 2; ++dh) {
      f32x4 c = acc[hh][dh];
      int colc = (h0 + hh) * 32 + dh * 16 + il;
#pragma unroll
      for (int e = 0; e < 4; ++e)
        lds_c[g4 * 4 + e][colc] = c[e] / dn[e];
    }
  }
  __syncthreads();

  // residual + LayerNorm: wave w handles rows w*4 .. w*4+3
#pragma unroll
  for (int rr = 0; rr < 4; ++rr) {
    int row = w * 4 + rr;
    f32x4 cv = *(f32x4*)&lds_c[row][lane * 4];
    const float* xp = xin + (size_t)(b * NS + i0 + row) * NM + lane * 4;
    f32x4 xv = *(const f32x4*)xp;
    f32x4 r;
#pragma unroll
    for (int e = 0; e < 4; ++e) r[e] = cv[e] + xv[e];
    float sm = r[0] + r[1] + r[2] + r[3];
    float sq = r[0] * r[0] + r[1] * r[1] + r[2] * r[2] + r[3] * r[3];
#pragma unroll
    for (int off = 32; off >= 1; off >>= 1) {
      sm += __shfl_xor(sm, off, 64);
      sq += __shfl_xor(sq, off, 64);
    }
    float mu = sm * (1.f / 256.f);
    float var = sq * (1.f / 256.f) - mu * mu;
    float inv = rsqrtf(var + 1e-5f);
    f32x4 gv = *(const f32x4*)(lng + lane * 4);
    f32x4 bv = *(const f32x4*)(lnb + lane * 4);
    f32x4 o;
#pragma unroll
    for (int e = 0; e < 4; ++e) o[e] = (r[e] - mu) * inv * gv[e] + bv[e];
    *(f32x4*)(xout + (size_t)(b * NS + i0 + row) * NM + lane * 4) = o;
  }
}

// ---------------------------------------------------------------------------
extern "C" void kernel_launch(void* const* d_in, const int* in_sizes, int n_in,
                              void* d_out, int out_size, void* d_ws, size_t ws_size,
                              hipStream_t stream)
{
  const int* adj = (const int*)d_in[0];
  const float* inputs = (const float*)d_in[1];
  const int* smask = (const int*)d_in[2];
  const int* typep = (const int*)d_in[3];
  const float* proj_w = (const float*)d_in[4];
  const float* proj_b = (const float*)d_in[5];
  const float* attn_w = (const float*)d_in[6];
  const float* attn_b = (const float*)d_in[7];
  const float* ln_g = (const float*)d_in[8];
  const float* ln_b = (const float*)d_in[9];
  float* out = (float*)d_out;

  char* ws = (char*)d_ws;
  unsigned int* pkc = (unsigned int*)(ws);                      // 2 MB
  unsigned int* pks = (unsigned int*)(ws + (2u << 20));         // 2 MB
  unsigned short* Pt = (unsigned short*)(ws + (4u << 20));      // 8 MB
  float* s1 = (float*)(ws + (12u << 20));                       // 512 KB
  float* s2 = (float*)(ws + (12u << 20) + (1u << 19));          // 512 KB
  float* x1 = (float*)(ws + (13u << 20));                       // 16 MB

  maskpack_kernel<<<2048, 256, 0, stream>>>(adj, smask, pkc, pks);

  for (int l = 0; l < NL; ++l) {
    const float* xin = (l == 0) ? inputs : x1;
    float* xout = (l == NL - 1) ? out : x1;
    proj_kernel<<<dim3(4, 256), 256, 0, stream>>>(
        xin, proj_w + (size_t)l * NH * NM * NDK, proj_b + (size_t)l * NH * NDK, Pt);
    s_kernel<<<512, 256, 0, stream>>>(Pt, attn_w + l * 64, attn_b + l, s1, s2);
    attn_kernel<<<1024, 256, 0, stream>>>(
        xin, Pt, s1, s2, pkc, pks, typep, l, ln_g + l * NM, ln_b + l * NM, xout);
  }
}

// Round 4
// 199.789 us; speedup vs baseline: 1.2086x; 1.2086x over previous
//
#include <hip/hip_runtime.h>
#include <hip/hip_bf16.h>
#include <math.h>

#define NB 16
#define NS 1024
#define NM 256
#define NH 8
#define NDK 32
#define NL 2

typedef __attribute__((ext_vector_type(4))) float f32x4;
typedef __attribute__((ext_vector_type(8))) short bf16x8;
typedef __attribute__((ext_vector_type(4))) short bf16x4u;

#if __has_builtin(__builtin_amdgcn_exp2f)
#define EXP2F(x) __builtin_amdgcn_exp2f(x)
#else
#define EXP2F(x) exp2f(x)
#endif

__device__ __forceinline__ unsigned short f2bf(float f) {
  unsigned int u = __builtin_bit_cast(unsigned int, f);
  unsigned int r = u + 0x7fffu + ((u >> 16) & 1u);
  return (unsigned short)(r >> 16);
}
__device__ __forceinline__ float bf2f(unsigned short h) {
  unsigned int u = ((unsigned int)h) << 16;
  return __builtin_bit_cast(float, u);
}

// ---------------------------------------------------------------------------
// Pack (smask || adj==0) and (smask) into bitmasks, 1 bit per (b,i,j).
__global__ __launch_bounds__(256) void maskpack_kernel(
    const int* __restrict__ adj, const int* __restrict__ sm,
    unsigned int* __restrict__ pkc, unsigned int* __restrict__ pks)
{
  int t = blockIdx.x * 256 + threadIdx.x;
  long base = (long)t * 32;
  const int4* a4 = (const int4*)(adj + base);
  const int4* m4 = (const int4*)(sm + base);
  union { int4 v[8]; int b[32]; } au, mu;
#pragma unroll
  for (int q = 0; q < 8; ++q) { au.v[q] = a4[q]; mu.v[q] = m4[q]; }
  unsigned int wc = 0, wsb = 0;
#pragma unroll
  for (int e = 0; e < 32; ++e) {
    unsigned int msk = mu.b[e] ? 1u : 0u;
    unsigned int cmb = (mu.b[e] || au.b[e] == 0) ? 1u : 0u;
    wsb |= msk << e;
    wc  |= cmb << e;
  }
  pkc[t] = wc; pks[t] = wsb;
}

// ---------------------------------------------------------------------------
// Projection GEMM -> Pt[b][h][d][s] (bf16), 64x64 tile, 4 waves.
__global__ __launch_bounds__(256) void proj_kernel(
    const float* __restrict__ x,        // (B*S, M)
    const float* __restrict__ pw,       // (H, M, DK) this layer
    const float* __restrict__ pb,       // (H*DK)
    unsigned short* __restrict__ Pt)    // (B,H,DK,S)
{
  __shared__ unsigned short As[64][40];
  __shared__ unsigned short Bs[64][40];

  int ct = blockIdx.x;
  int rt = blockIdx.y;
  int t = threadIdx.x;
  int w = t >> 6, lane = t & 63;
  int il = lane & 15, g4 = lane >> 4;
  int wi = w >> 1, wc = w & 1;

  f32x4 acc[2][2] = {};

  int arow = t >> 2, akoff = (t & 3) * 8;
  int bcol = t & 63, bk0 = (t >> 6) * 8;
  int hd = ct * 64 + bcol;
  int h = hd >> 5, d = hd & 31;

  for (int k0 = 0; k0 < NM; k0 += 32) {
    const float* xp = x + (size_t)(rt * 64 + arow) * NM + k0 + akoff;
    f32x4 v0 = *(const f32x4*)xp;
    f32x4 v1 = *(const f32x4*)(xp + 4);
    bf16x8 av;
    av[0] = f2bf(v0[0]); av[1] = f2bf(v0[1]); av[2] = f2bf(v0[2]); av[3] = f2bf(v0[3]);
    av[4] = f2bf(v1[0]); av[5] = f2bf(v1[1]); av[6] = f2bf(v1[2]); av[7] = f2bf(v1[3]);
    *(bf16x8*)&As[arow][akoff] = av;
    const float* wp = pw + (size_t)h * NM * NDK + (size_t)(k0 + bk0) * NDK + d;
    bf16x8 bv;
#pragma unroll
    for (int q = 0; q < 8; ++q) bv[q] = f2bf(wp[q * NDK]);
    *(bf16x8*)&Bs[bcol][bk0] = bv;
    __syncthreads();

    bf16x8 af0 = *(bf16x8*)&As[wi * 32 + il][g4 * 8];
    bf16x8 af1 = *(bf16x8*)&As[wi * 32 + 16 + il][g4 * 8];
    bf16x8 bf0 = *(bf16x8*)&Bs[wc * 32 + il][g4 * 8];
    bf16x8 bf1 = *(bf16x8*)&Bs[wc * 32 + 16 + il][g4 * 8];
    acc[0][0] = __builtin_amdgcn_mfma_f32_16x16x32_bf16(af0, bf0, acc[0][0], 0, 0, 0);
    acc[0][1] = __builtin_amdgcn_mfma_f32_16x16x32_bf16(af0, bf1, acc[0][1], 0, 0, 0);
    acc[1][0] = __builtin_amdgcn_mfma_f32_16x16x32_bf16(af1, bf0, acc[1][0], 0, 0, 0);
    acc[1][1] = __builtin_amdgcn_mfma_f32_16x16x32_bf16(af1, bf1, acc[1][1], 0, 0, 0);
    __syncthreads();
  }

#pragma unroll
  for (int ih = 0; ih < 2; ++ih) {
#pragma unroll
    for (int dh = 0; dh < 2; ++dh) {
      int colhd = ct * 64 + wc * 32 + dh * 16 + il;
      int hh = colhd >> 5, dd = colhd & 31;
      float bias = pb[colhd];
      int r0 = rt * 64 + wi * 32 + ih * 16 + g4 * 4;
      int bb = r0 >> 10, ss = r0 & 1023;
      f32x4 c = acc[ih][dh];
      unsigned short ov[4];
#pragma unroll
      for (int e = 0; e < 4; ++e) ov[e] = f2bf(c[e] + bias);
      size_t idx = ((size_t)(bb * NH + hh) * NDK + dd) * NS + ss;
      *(bf16x4u*)(Pt + idx) = *(bf16x4u*)ov;
    }
  }
}

// ---------------------------------------------------------------------------
// s1/s2 PRE-SCALED by log2(e) so attn uses native exp2.
__global__ __launch_bounds__(256) void s_kernel(
    const unsigned short* __restrict__ Pt,
    const float* __restrict__ aw,   // 64 floats this layer
    const float* __restrict__ abp,  // attn_b + l
    float* __restrict__ s1o, float* __restrict__ s2o)
{
  const float LOG2E = 1.4426950408889634f;
  int t = blockIdx.x * 256 + threadIdx.x;   // (b*H+h)*S + s
  int bh = t >> 10, s = t & 1023;
  const unsigned short* p = Pt + (size_t)bh * NDK * NS + s;
  float s1 = 0.f, s2 = 0.f;
#pragma unroll
  for (int dd = 0; dd < NDK; ++dd) {
    float pv = bf2f(p[dd * NS]);
    s1 += pv * aw[dd];
    s2 += pv * aw[32 + dd];
  }
  s1o[t] = s1 * LOG2E;
  s2o[t] = (s2 + abp[0]) * LOG2E;
}

// ---------------------------------------------------------------------------
// Fused attention + residual + LayerNorm.
// Block = one (b, 32-row i-tile), 512 threads = 8 waves; wave w owns head w.
// Grid = B * (S/32) = 512 blocks -> 2 blocks/CU -> 16 waves/CU.
// Softmax denominator computed by a 3rd MFMA with an all-ones B operand:
// D-layout row-sums land exactly in the rows each lane normalizes.
__global__ __launch_bounds__(512) void attn_kernel(
    const float* __restrict__ xin,            // residual input (B,S,M) f32
    const unsigned short* __restrict__ Pt,    // (B,H,DK,S) bf16
    const float* __restrict__ s1a,            // (B,H,S), pre-scaled log2e
    const float* __restrict__ s2a,            // (B,H,S), pre-scaled, incl +ab
    const unsigned int* __restrict__ pkc,     // combined mask bits
    const unsigned int* __restrict__ pks,     // smask-only bits
    const int* __restrict__ typep,
    int layer,
    const float* __restrict__ lng,
    const float* __restrict__ lnb,
    float* __restrict__ xout)
{
  __shared__ float lds_c[32][260];   // concat tile, stride 260 (2-way max)

  int blk = blockIdx.x;
  int b = blk >> 5, it = blk & 31, i0 = it * 32;
  int t = threadIdx.x, w = t >> 6, lane = t & 63;   // w = head
  int il = lane & 15, g4 = lane >> 4;
  const unsigned char* pkb =
      (const unsigned char*)((typep[0] == 1 && layer > 0) ? pks : pkc);
  size_t rowbase0 = ((size_t)(b * NS + i0 + il) * NS) >> 3;       // byte idx
  size_t rowbase1 = ((size_t)(b * NS + i0 + 16 + il) * NS) >> 3;

  float s1v[2];
#pragma unroll
  for (int ih = 0; ih < 2; ++ih)
    s1v[ih] = s1a[(size_t)(b * NH + w) * NS + i0 + ih * 16 + il];

  bf16x8 ones;
#pragma unroll
  for (int e = 0; e < 8; ++e) ones[e] = (short)0x3F80;   // bf16 1.0

  f32x4 acc[2][2] = {};      // [ih][dh]
  f32x4 acc_den[2] = {};     // [ih] row-sum via ones-MFMA
  const unsigned short* ptb = Pt + (size_t)(b * NH + w) * NDK * NS;
  const float* s2b = s2a + (size_t)(b * NH + w) * NS;

  for (int j0 = 0; j0 < NS; j0 += 32) {
    int jb = j0 + g4 * 8;
    unsigned int mb[2];
    mb[0] = pkb[rowbase0 + (jb >> 3)];
    mb[1] = pkb[rowbase1 + (jb >> 3)];
    f32x4 s2lo = *(const f32x4*)(s2b + jb);
    f32x4 s2hi = *(const f32x4*)(s2b + jb + 4);
    float s2v[8] = {s2lo[0], s2lo[1], s2lo[2], s2lo[3],
                    s2hi[0], s2hi[1], s2hi[2], s2hi[3]};
    bf16x8 bf0 = *(const bf16x8*)(ptb + (size_t)il * NS + jb);
    bf16x8 bf1 = *(const bf16x8*)(ptb + (size_t)(16 + il) * NS + jb);
#pragma unroll
    for (int ih = 0; ih < 2; ++ih) {
      float wv[8];
#pragma unroll
      for (int e = 0; e < 8; ++e) {
        float sc = s1v[ih] + s2v[e];
        sc = fmaxf(sc, 0.2f * sc);             // LeakyReLU(0.2) (scale>0 commutes)
        float ex = EXP2F(sc);                  // scores pre-scaled by log2e
        wv[e] = (mb[ih] & (1u << e)) ? 0.f : ex;
      }
      bf16x8 af;
#pragma unroll
      for (int e = 0; e < 8; ++e)
        af[e] = (short)__bfloat16_as_ushort(__float2bfloat16(wv[e]));
      acc[ih][0] = __builtin_amdgcn_mfma_f32_16x16x32_bf16(af, bf0, acc[ih][0], 0, 0, 0);
      acc[ih][1] = __builtin_amdgcn_mfma_f32_16x16x32_bf16(af, bf1, acc[ih][1], 0, 0, 0);
      acc_den[ih] = __builtin_amdgcn_mfma_f32_16x16x32_bf16(af, ones, acc_den[ih], 0, 0, 0);
    }
  }

  // normalize + scatter concat tile to LDS (D layout: col=il, row=g4*4+e)
#pragma unroll
  for (int ih = 0; ih < 2; ++ih) {
    f32x4 dn = acc_den[ih];
    f32x4 rd;
#pragma unroll
    for (int e = 0; e < 4; ++e) rd[e] = __builtin_amdgcn_rcpf(dn[e]);
#pragma unroll
    for (int dh = 0; dh < 2; ++dh) {
      f32x4 c = acc[ih][dh];
      int colc = w * 32 + dh * 16 + il;
#pragma unroll
      for (int e = 0; e < 4; ++e)
        lds_c[ih * 16 + g4 * 4 + e][colc] = c[e] * rd[e];
    }
  }
  __syncthreads();

  // residual + LayerNorm: wave w handles rows w*4 .. w*4+3
#pragma unroll
  for (int rr = 0; rr < 4; ++rr) {
    int row = w * 4 + rr;
    f32x4 cv = *(f32x4*)&lds_c[row][lane * 4];
    const float* xp = xin + (size_t)(b * NS + i0 + row) * NM + lane * 4;
    f32x4 xv = *(const f32x4*)xp;
    f32x4 r;
#pragma unroll
    for (int e = 0; e < 4; ++e) r[e] = cv[e] + xv[e];
    float sm = r[0] + r[1] + r[2] + r[3];
    float sq = r[0] * r[0] + r[1] * r[1] + r[2] * r[2] + r[3] * r[3];
#pragma unroll
    for (int off = 32; off >= 1; off >>= 1) {
      sm += __shfl_xor(sm, off, 64);
      sq += __shfl_xor(sq, off, 64);
    }
    float mu = sm * (1.f / 256.f);
    float var = sq * (1.f / 256.f) - mu * mu;
    float inv = rsqrtf(var + 1e-5f);
    f32x4 gv = *(const f32x4*)(lng + lane * 4);
    f32x4 bv = *(const f32x4*)(lnb + lane * 4);
    f32x4 o;
#pragma unroll
    for (int e = 0; e < 4; ++e) o[e] = (r[e] - mu) * inv * gv[e] + bv[e];
    *(f32x4*)(xout + (size_t)(b * NS + i0 + row) * NM + lane * 4) = o;
  }
}

// ---------------------------------------------------------------------------
extern "C" void kernel_launch(void* const* d_in, const int* in_sizes, int n_in,
                              void* d_out, int out_size, void* d_ws, size_t ws_size,
                              hipStream_t stream)
{
  const int* adj = (const int*)d_in[0];
  const float* inputs = (const float*)d_in[1];
  const int* smask = (const int*)d_in[2];
  const int* typep = (const int*)d_in[3];
  const float* proj_w = (const float*)d_in[4];
  const float* proj_b = (const float*)d_in[5];
  const float* attn_w = (const float*)d_in[6];
  const float* attn_b = (const float*)d_in[7];
  const float* ln_g = (const float*)d_in[8];
  const float* ln_b = (const float*)d_in[9];
  float* out = (float*)d_out;

  char* ws = (char*)d_ws;
  unsigned int* pkc = (unsigned int*)(ws);                      // 2 MB
  unsigned int* pks = (unsigned int*)(ws + (2u << 20));         // 2 MB
  unsigned short* Pt = (unsigned short*)(ws + (4u << 20));      // 8 MB
  float* s1 = (float*)(ws + (12u << 20));                       // 512 KB
  float* s2 = (float*)(ws + (12u << 20) + (1u << 19));          // 512 KB
  float* x1 = (float*)(ws + (13u << 20));                       // 16 MB

  maskpack_kernel<<<2048, 256, 0, stream>>>(adj, smask, pkc, pks);

  for (int l = 0; l < NL; ++l) {
    const float* xin = (l == 0) ? inputs : x1;
    float* xout = (l == NL - 1) ? out : x1;
    proj_kernel<<<dim3(4, 256), 256, 0, stream>>>(
        xin, proj_w + (size_t)l * NH * NM * NDK, proj_b + (size_t)l * NH * NDK, Pt);
    s_kernel<<<512, 256, 0, stream>>>(Pt, attn_w + l * 64, attn_b + l, s1, s2);
    attn_kernel<<<512, 512, 0, stream>>>(
        xin, Pt, s1, s2, pkc, pks, typep, l, ln_g + l * NM, ln_b + l * NM, xout);
  }
}